// Round 1
// baseline (268.455 us; speedup 1.0000x reference)
//
#include <hip/hip_runtime.h>
#include <math.h>

// ChamferDistanceL1: B=8, N=M=4096, fp32.
// Strategy: brute-force NN both directions. Query coords in registers, DB
// slice (1024 pts) in LDS as float4 (ds_read_b128 broadcast, wave-uniform).
// Partial mins merged with atomicMin on uint bit pattern (dist >= 0 so float
// order == uint order). Finalize kernel sums and scales.

#define NN_BLK 256
#define DB_SLICE 1024

__global__ __launch_bounds__(NN_BLK) void nn_min_kernel(
    const float* __restrict__ q, const float* __restrict__ db,
    unsigned int* __restrict__ omin, int Nq, int Ndb) {
  __shared__ float4 sdb[DB_SLICE];
  const int b = blockIdx.z;
  const int j0 = blockIdx.y * DB_SLICE;
  const int i = blockIdx.x * NN_BLK + threadIdx.x;
  const float* __restrict__ qb  = q  + (size_t)b * Nq  * 3;
  const float* __restrict__ dbb = db + (size_t)b * Ndb * 3;

  const int jend = min(DB_SLICE, Ndb - j0);
  for (int t = threadIdx.x; t < jend; t += NN_BLK) {
    const int j = j0 + t;
    sdb[t] = make_float4(dbb[3 * j + 0], dbb[3 * j + 1], dbb[3 * j + 2], 0.0f);
  }
  __syncthreads();

  if (i >= Nq) return;
  const float qx = qb[3 * i + 0];
  const float qy = qb[3 * i + 1];
  const float qz = qb[3 * i + 2];

  float dmin = 3.0e38f;
#pragma unroll 8
  for (int t = 0; t < jend; ++t) {
    const float4 p = sdb[t];
    const float d = fabsf(qx - p.x) + fabsf(qy - p.y) + fabsf(qz - p.z);
    dmin = fminf(dmin, d);
  }
  atomicMin(&omin[(size_t)b * Nq + i], __float_as_uint(dmin));
}

__global__ __launch_bounds__(1024) void chamfer_finalize_kernel(
    const unsigned int* __restrict__ mx, const unsigned int* __restrict__ my,
    float* __restrict__ out, int nx, int ny, float sx_scale, float sy_scale) {
  float sx = 0.0f, sy = 0.0f;
  for (int i = threadIdx.x; i < nx; i += 1024) sx += __uint_as_float(mx[i]);
  for (int i = threadIdx.x; i < ny; i += 1024) sy += __uint_as_float(my[i]);
#pragma unroll
  for (int o = 32; o > 0; o >>= 1) {
    sx += __shfl_down(sx, o, 64);
    sy += __shfl_down(sy, o, 64);
  }
  __shared__ float rx[16], ry[16];
  const int wid = threadIdx.x >> 6;
  const int lane = threadIdx.x & 63;
  if (lane == 0) { rx[wid] = sx; ry[wid] = sy; }
  __syncthreads();
  if (threadIdx.x == 0) {
    float tx = 0.0f, ty = 0.0f;
    for (int w = 0; w < 16; ++w) { tx += rx[w]; ty += ry[w]; }
    out[0] = tx * sx_scale + ty * sy_scale;
  }
}

extern "C" void kernel_launch(void* const* d_in, const int* in_sizes, int n_in,
                              void* d_out, int out_size, void* d_ws, size_t ws_size,
                              hipStream_t stream) {
  const float* x = (const float*)d_in[0];
  const float* y = (const float*)d_in[1];
  // Shapes fixed by the reference setup: x [8,4096,3], y [8,4096,3].
  const int B = 8;
  const int N = in_sizes[0] / (B * 3);
  const int M = in_sizes[1] / (B * 3);

  unsigned int* minx = (unsigned int*)d_ws;          // B*N entries
  unsigned int* miny = minx + (size_t)B * N;         // B*M entries

  // Init mins to 0x7f7f7f7f == 3.39e38f (big sentinel, graph-capture-safe).
  hipMemsetAsync(d_ws, 0x7f, (size_t)(B * N + B * M) * sizeof(unsigned int), stream);

  dim3 blk(NN_BLK);
  dim3 gx((N + NN_BLK - 1) / NN_BLK, (M + DB_SLICE - 1) / DB_SLICE, B);
  dim3 gy((M + NN_BLK - 1) / NN_BLK, (N + DB_SLICE - 1) / DB_SLICE, B);
  // cham_x: query = x, db = y
  nn_min_kernel<<<gx, blk, 0, stream>>>(x, y, minx, N, M);
  // cham_y: query = y, db = x
  nn_min_kernel<<<gy, blk, 0, stream>>>(y, x, miny, M, N);

  chamfer_finalize_kernel<<<1, 1024, 0, stream>>>(
      minx, miny, (float*)d_out, B * N, B * M,
      1.0f / (float)(B * N), 1.0f / (float)(B * M));
}

// Round 2
// 105.197 us; speedup vs baseline: 2.5519x; 2.5519x over previous
//
#include <hip/hip_runtime.h>
#include <math.h>

// ChamferDistanceL1: B=8, N=M=4096, fp32.
// R2: - Q=4 queries/thread: each ds_read_b128 (wave-uniform broadcast) now
//       feeds 24 VALU insts instead of 6 -> LDS pipe (shared per CU, ~12cyc
//       per b128) no longer oversubscribed 4x by the 4 SIMDs.
//     - 4 independent fmin chains per lane -> ILP over the 4-cyc dep latency.
//     - Both chamfer directions in ONE launch (blockIdx.z = 2*B) -> 1024
//       blocks = 4 blocks/CU instead of 2x serial 512-block kernels.
// Partial mins merged with atomicMin on uint bit pattern (dist >= 0 so float
// order == uint order). Finalize kernel sums and scales.

#define NN_BLK 256
#define QPT 4          // queries per thread
#define DB_SLICE 256   // db points staged in LDS per block

__global__ __launch_bounds__(NN_BLK) void nn_min_kernel(
    const float* __restrict__ x, const float* __restrict__ y,
    unsigned int* __restrict__ minx, unsigned int* __restrict__ miny,
    int N, int M) {
  __shared__ float4 sdb[DB_SLICE];

  const int bz  = blockIdx.z;
  const int b   = bz >> 1;
  const int dir = bz & 1;  // 0: q=x db=y, 1: q=y db=x
  const float* __restrict__ q  = dir ? y : x;
  const float* __restrict__ db = dir ? x : y;
  unsigned int* __restrict__ omin = dir ? miny : minx;
  const int Nq  = dir ? M : N;
  const int Ndb = dir ? N : M;

  const float* __restrict__ qb  = q  + (size_t)b * Nq  * 3;
  const float* __restrict__ dbb = db + (size_t)b * Ndb * 3;

  // Stage DB slice into LDS as float4.
  const int j0 = blockIdx.y * DB_SLICE;
  const int jend = min(DB_SLICE, Ndb - j0);
  for (int t = threadIdx.x; t < jend; t += NN_BLK) {
    const int j = j0 + t;
    sdb[t] = make_float4(dbb[3 * j + 0], dbb[3 * j + 1], dbb[3 * j + 2], 0.0f);
  }
  __syncthreads();

  // Q=4 queries per thread, strided by NN_BLK for coalescing.
  const int iBase = blockIdx.x * (NN_BLK * QPT) + threadIdx.x;
  float qx[QPT], qy[QPT], qz[QPT], dmin[QPT];
#pragma unroll
  for (int k = 0; k < QPT; ++k) {
    const int i = iBase + k * NN_BLK;
    const int ic = (i < Nq) ? i : (Nq - 1);
    qx[k] = qb[3 * ic + 0];
    qy[k] = qb[3 * ic + 1];
    qz[k] = qb[3 * ic + 2];
    dmin[k] = 3.0e38f;
  }

#pragma unroll 4
  for (int t = 0; t < jend; ++t) {
    const float4 p = sdb[t];
#pragma unroll
    for (int k = 0; k < QPT; ++k) {
      const float d =
          fabsf(qx[k] - p.x) + fabsf(qy[k] - p.y) + fabsf(qz[k] - p.z);
      dmin[k] = fminf(dmin[k], d);
    }
  }

#pragma unroll
  for (int k = 0; k < QPT; ++k) {
    const int i = iBase + k * NN_BLK;
    if (i < Nq) atomicMin(&omin[(size_t)b * Nq + i], __float_as_uint(dmin[k]));
  }
}

__global__ __launch_bounds__(1024) void chamfer_finalize_kernel(
    const unsigned int* __restrict__ mx, const unsigned int* __restrict__ my,
    float* __restrict__ out, int nx, int ny, float sx_scale, float sy_scale) {
  float sx = 0.0f, sy = 0.0f;
  for (int i = threadIdx.x; i < nx; i += 1024) sx += __uint_as_float(mx[i]);
  for (int i = threadIdx.x; i < ny; i += 1024) sy += __uint_as_float(my[i]);
#pragma unroll
  for (int o = 32; o > 0; o >>= 1) {
    sx += __shfl_down(sx, o, 64);
    sy += __shfl_down(sy, o, 64);
  }
  __shared__ float rx[16], ry[16];
  const int wid = threadIdx.x >> 6;
  const int lane = threadIdx.x & 63;
  if (lane == 0) { rx[wid] = sx; ry[wid] = sy; }
  __syncthreads();
  if (threadIdx.x == 0) {
    float tx = 0.0f, ty = 0.0f;
    for (int w = 0; w < 16; ++w) { tx += rx[w]; ty += ry[w]; }
    out[0] = tx * sx_scale + ty * sy_scale;
  }
}

extern "C" void kernel_launch(void* const* d_in, const int* in_sizes, int n_in,
                              void* d_out, int out_size, void* d_ws, size_t ws_size,
                              hipStream_t stream) {
  const float* x = (const float*)d_in[0];
  const float* y = (const float*)d_in[1];
  const int B = 8;
  const int N = in_sizes[0] / (B * 3);
  const int M = in_sizes[1] / (B * 3);  // N == M == 4096 for this problem

  unsigned int* minx = (unsigned int*)d_ws;   // B*N entries
  unsigned int* miny = minx + (size_t)B * N;  // B*M entries

  // Init mins to 0x7f7f7f7f == 3.39e38f (big sentinel, graph-capture-safe).
  hipMemsetAsync(d_ws, 0x7f, (size_t)(B * N + B * M) * sizeof(unsigned int), stream);

  // N == M so one grid covers both directions via blockIdx.z = 2*B.
  dim3 blk(NN_BLK);
  dim3 grd((N + NN_BLK * QPT - 1) / (NN_BLK * QPT),
           (M + DB_SLICE - 1) / DB_SLICE, 2 * B);
  nn_min_kernel<<<grd, blk, 0, stream>>>(x, y, minx, miny, N, M);

  chamfer_finalize_kernel<<<1, 1024, 0, stream>>>(
      minx, miny, (float*)d_out, B * N, B * M,
      1.0f / (float)(B * N), 1.0f / (float)(B * M));
}

// Round 3
// 95.072 us; speedup vs baseline: 2.8237x; 1.1065x over previous
//
#include <hip/hip_runtime.h>
#include <math.h>

// ChamferDistanceL1: B=8, N=M=4096, fp32.
// R3: single fused kernel + one 4B memset (R2 lost ~65us to 4 serial graph
// nodes: memset/nn/finalize). Each block finalizes 64 queries against the
// FULL db (staged in LDS 1024-pt slices), reduces min->sum in-block, and
// does ONE atomicAdd(d_out). 16 groups x 16 threads, QPT=4 queries/thread
// keeps the 24-VALU-per-ds_read_b128 amortization from R2. Grid 1024 blocks,
// LDS 20KB -> 4 blocks/CU = 16 waves/CU (R2 was 8).

#define BLK 256
#define QPB 64       // queries per block
#define NGRP 16      // groups (g = tid>>4), each scans 1/16 of a slice
#define QPT 4        // queries per thread (16 thr/group * 4 = 64 = QPB)
#define SLICE 1024   // db points staged in LDS per slice
#define GRANGE (SLICE / NGRP)  // 64 db points per group per slice

__global__ __launch_bounds__(BLK) void chamfer_fused_kernel(
    const float* __restrict__ x, const float* __restrict__ y,
    float* __restrict__ out, int N, int M, float sx, float sy) {
  __shared__ float4 sdb[SLICE];        // 16 KB
  __shared__ float pmin[NGRP][QPB];    // 4 KB

  const int dir = blockIdx.z;  // 0: q=x db=y, 1: q=y db=x
  const int b = blockIdx.y;
  const float* __restrict__ q  = dir ? y : x;
  const float* __restrict__ db = dir ? x : y;
  const int Nq  = dir ? M : N;
  const int Ndb = dir ? N : M;
  const float scale = dir ? sy : sx;

  const float* __restrict__ qb  = q  + (size_t)b * Nq  * 3;
  const float* __restrict__ dbb = db + (size_t)b * Ndb * 3;

  const int t = threadIdx.x;
  const int g = t >> 4;   // group id   [0,16)
  const int u = t & 15;   // lane-in-group

  // Load this thread's 4 queries into registers.
  const int q0 = blockIdx.x * QPB;
  float qx[QPT], qy[QPT], qz[QPT], dmin[QPT];
#pragma unroll
  for (int k = 0; k < QPT; ++k) {
    int qi = q0 + u + 16 * k;
    if (qi >= Nq) qi = Nq - 1;  // N divides evenly here; safe clamp anyway
    qx[k] = qb[3 * qi + 0];
    qy[k] = qb[3 * qi + 1];
    qz[k] = qb[3 * qi + 2];
    dmin[k] = 3.0e38f;
  }

  // Scan the full DB in LDS slices; mins accumulate across slices.
  for (int s0 = 0; s0 < Ndb; s0 += SLICE) {
    const int send = min(SLICE, Ndb - s0);
    for (int p = t; p < send; p += BLK) {
      const int j = s0 + p;
      sdb[p] = make_float4(dbb[3 * j + 0], dbb[3 * j + 1], dbb[3 * j + 2], 0.0f);
    }
    __syncthreads();

    const int base = g * GRANGE;
    const int lim = min(GRANGE, send - base);
#pragma unroll 4
    for (int tt = 0; tt < lim; ++tt) {
      const float4 p = sdb[base + tt];
#pragma unroll
      for (int k = 0; k < QPT; ++k) {
        const float d =
            fabsf(qx[k] - p.x) + fabsf(qy[k] - p.y) + fabsf(qz[k] - p.z);
        dmin[k] = fminf(dmin[k], d);
      }
    }
    __syncthreads();
  }

  // Combine the 16 group-partials per query, then sum the 64 finals.
#pragma unroll
  for (int k = 0; k < QPT; ++k) pmin[g][u + 16 * k] = dmin[k];
  __syncthreads();

  if (t < QPB) {  // first wave only; t indexes the query within the block
    float m = pmin[0][t];
#pragma unroll
    for (int gg = 1; gg < NGRP; ++gg) m = fminf(m, pmin[gg][t]);
#pragma unroll
    for (int o = 32; o > 0; o >>= 1) m += __shfl_down(m, o, 64);
    if (t == 0) atomicAdd(out, m * scale);
  }
}

extern "C" void kernel_launch(void* const* d_in, const int* in_sizes, int n_in,
                              void* d_out, int out_size, void* d_ws, size_t ws_size,
                              hipStream_t stream) {
  const float* x = (const float*)d_in[0];
  const float* y = (const float*)d_in[1];
  const int B = 8;
  const int N = in_sizes[0] / (B * 3);
  const int M = in_sizes[1] / (B * 3);  // N == M == 4096 for this problem

  float* out = (float*)d_out;
  // Zero the scalar accumulator (d_out is poisoned before every launch).
  hipMemsetAsync(out, 0, sizeof(float), stream);

  dim3 blk(BLK);
  dim3 grd((N + QPB - 1) / QPB, B, 2);  // N == M: same x-extent both dirs
  chamfer_fused_kernel<<<grd, blk, 0, stream>>>(
      x, y, out, N, M, 1.0f / (float)(B * N), 1.0f / (float)(B * M));
}

// Round 4
// 90.657 us; speedup vs baseline: 2.9612x; 1.0487x over previous
//
#include <hip/hip_runtime.h>
#include <math.h>

// ChamferDistanceL1: B=8, N=M=4096, fp32.
// R4: fix R3's 4-way LDS bank conflict + raise occupancy.
//  - sdb padded to [NGRP][GRANGE+1]: group base stride = 33 float4 = 132
//    dwords === 4 (mod 32), so the 4 groups inside a wave read disjoint
//    bank quads -> conflict-free (R3 had 8.4M conflict cycles: stride 64
//    float4 === 0 mod 32 banks, 4-way).
//  - BLK=512 (8 waves), NGRP=32, GRANGE=32: grid stays 1024 blocks =
//    4 blocks/CU x 8 waves = 32 waves/CU (R3: 16). LDS 24.4KB -> fits 4/CU.
// Single fused kernel + 4B memset; block finalizes its 64 queries against
// the full 4096-pt db and does one atomicAdd(d_out).

#define BLK 512
#define QPB 64       // queries per block
#define NGRP 32      // groups of 16 lanes; group g scans 1/32 of each slice
#define QPT 4        // queries per thread (16 lanes * 4 = 64 = QPB)
#define SLICE 1024   // db points staged in LDS per slice
#define GRANGE (SLICE / NGRP)  // 32 db points per group per slice

__global__ __launch_bounds__(BLK) void chamfer_fused_kernel(
    const float* __restrict__ x, const float* __restrict__ y,
    float* __restrict__ out, int N, int M, float sx, float sy) {
  __shared__ float4 sdb[NGRP][GRANGE + 1];  // padded: bank-conflict-free
  __shared__ float pmin[NGRP][QPB];         // 8 KB

  const int dir = blockIdx.z;  // 0: q=x db=y, 1: q=y db=x
  const int b = blockIdx.y;
  const float* __restrict__ q  = dir ? y : x;
  const float* __restrict__ db = dir ? x : y;
  const int Nq  = dir ? M : N;
  const int Ndb = dir ? N : M;
  const float scale = dir ? sy : sx;

  const float* __restrict__ qb  = q  + (size_t)b * Nq  * 3;
  const float* __restrict__ dbb = db + (size_t)b * Ndb * 3;

  const int t = threadIdx.x;
  const int g = t >> 4;   // group id   [0,32)
  const int u = t & 15;   // lane-in-group

  // Load this thread's 4 queries into registers.
  const int q0 = blockIdx.x * QPB;
  float qx[QPT], qy[QPT], qz[QPT], dmin[QPT];
#pragma unroll
  for (int k = 0; k < QPT; ++k) {
    int qi = q0 + u + 16 * k;
    if (qi >= Nq) qi = Nq - 1;
    qx[k] = qb[3 * qi + 0];
    qy[k] = qb[3 * qi + 1];
    qz[k] = qb[3 * qi + 2];
    dmin[k] = 3.0e38f;
  }

  // Scan the full DB in LDS slices; mins accumulate across slices.
  for (int s0 = 0; s0 < Ndb; s0 += SLICE) {
    const int send = min(SLICE, Ndb - s0);
    for (int p = t; p < send; p += BLK) {
      const int j = s0 + p;
      sdb[p >> 5][p & 31] =
          make_float4(dbb[3 * j + 0], dbb[3 * j + 1], dbb[3 * j + 2], 0.0f);
    }
    __syncthreads();

    const int lim = min(GRANGE, send - g * GRANGE);
#pragma unroll 8
    for (int tt = 0; tt < lim; ++tt) {
      const float4 p = sdb[g][tt];
#pragma unroll
      for (int k = 0; k < QPT; ++k) {
        const float d =
            fabsf(qx[k] - p.x) + fabsf(qy[k] - p.y) + fabsf(qz[k] - p.z);
        dmin[k] = fminf(dmin[k], d);
      }
    }
    __syncthreads();
  }

  // Combine the 32 group-partials per query, then sum the 64 finals.
#pragma unroll
  for (int k = 0; k < QPT; ++k) pmin[g][u + 16 * k] = dmin[k];
  __syncthreads();

  if (t < QPB) {  // first wave only; t indexes the query within the block
    float m = pmin[0][t];
#pragma unroll
    for (int gg = 1; gg < NGRP; ++gg) m = fminf(m, pmin[gg][t]);
#pragma unroll
    for (int o = 32; o > 0; o >>= 1) m += __shfl_down(m, o, 64);
    if (t == 0) atomicAdd(out, m * scale);
  }
}

extern "C" void kernel_launch(void* const* d_in, const int* in_sizes, int n_in,
                              void* d_out, int out_size, void* d_ws, size_t ws_size,
                              hipStream_t stream) {
  const float* x = (const float*)d_in[0];
  const float* y = (const float*)d_in[1];
  const int B = 8;
  const int N = in_sizes[0] / (B * 3);
  const int M = in_sizes[1] / (B * 3);  // N == M == 4096 for this problem

  float* out = (float*)d_out;
  // Zero the scalar accumulator (d_out is poisoned before every launch).
  hipMemsetAsync(out, 0, sizeof(float), stream);

  dim3 blk(BLK);
  dim3 grd((N + QPB - 1) / QPB, B, 2);  // N == M: same x-extent both dirs
  chamfer_fused_kernel<<<grd, blk, 0, stream>>>(
      x, y, out, N, M, 1.0f / (float)(B * N), 1.0f / (float)(B * M));
}